// Round 2
// baseline (691.387 us; speedup 1.0000x reference)
//
#include <hip/hip_runtime.h>
#include <math.h>

// Problem constants (match reference)
constexpr int BATCH = 8;
constexpr int EDIM  = 32;
constexpr int HDIM  = 512;
constexpr int WDIM  = 512;
constexpr int HW    = HDIM * WDIM;          // 262144 pixels per sample
constexpr int NSEG  = 33;                   // NUM_INST + 1 (segment 0 = background)
constexpr int NINST = 32;
constexpr float DELTA_V = 0.5f;
constexpr float TWO_DELTA_D = 3.0f;         // 2 * DELTA_D
constexpr float ALPHA = 1.0f, BETA = 1.0f, GAMMA = 0.001f;

constexpr int TPB  = 256;                   // threads per block
constexpr int PXT  = 4;                     // pixels per thread (float4)
constexpr int TILE = TPB * PXT;             // 1024 pixels per block-tile
constexpr int NTILES = HW / TILE;           // 256 tiles per sample
constexpr int BPS  = 128;                   // blocks per sample (each handles 2 tiles)
constexpr int EC   = 8;                     // e-chunk (float4 regs per buffer)
constexpr int NCHUNK = EDIM / EC;           // 4 chunks

// ---------------- workspace zeroing ----------------
__global__ void k_zero(float* __restrict__ p, int n) {
    int i = blockIdx.x * blockDim.x + threadIdx.x;
    if (i < n) p[i] = 0.0f;
}

// ---------------- pass 1: segment sums + counts ----------------
// sums layout: [b][e*NSEG + m]  (matches LDS [e][m], stride 33 -> bank (e+m)%32)
__global__ __launch_bounds__(TPB) void k_segsum(const float* __restrict__ emb,
                                                const int* __restrict__ msk,
                                                float* __restrict__ sums,
                                                float* __restrict__ cnts) {
    __shared__ float s_sum[EDIM * NSEG];
    __shared__ float s_cnt[NSEG];
    const int b = blockIdx.y;
    for (int i = threadIdx.x; i < EDIM * NSEG; i += TPB) s_sum[i] = 0.0f;
    if (threadIdx.x < NSEG) s_cnt[threadIdx.x] = 0.0f;
    __syncthreads();

    const float* embB = emb + (size_t)b * EDIM * HW;
    const int*   mskB = msk + (size_t)b * HW;

    for (int t = blockIdx.x; t < NTILES; t += BPS) {
        const int p0 = t * TILE + threadIdx.x * PXT;
        const int4 m4 = *reinterpret_cast<const int4*>(mskB + p0);
        atomicAdd(&s_cnt[m4.x], 1.0f);
        atomicAdd(&s_cnt[m4.y], 1.0f);
        atomicAdd(&s_cnt[m4.z], 1.0f);
        atomicAdd(&s_cnt[m4.w], 1.0f);

        // Double-buffered register staging: 8 float4 loads in flight while
        // the previous 8 are consumed by LDS atomics. All indices static
        // after full unroll (runtime-indexed reg arrays spill to scratch).
        float4 buf[2][EC];
#pragma unroll
        for (int e = 0; e < EC; ++e)
            buf[0][e] = *reinterpret_cast<const float4*>(embB + (size_t)e * HW + p0);
#pragma unroll
        for (int c = 0; c < NCHUNK; ++c) {
            if (c < NCHUNK - 1) {
#pragma unroll
                for (int e = 0; e < EC; ++e)
                    buf[(c + 1) & 1][e] = *reinterpret_cast<const float4*>(
                        embB + (size_t)((c + 1) * EC + e) * HW + p0);
            }
#pragma unroll
            for (int e = 0; e < EC; ++e) {
                const float4 v = buf[c & 1][e];
                float* se = s_sum + (c * EC + e) * NSEG;
                atomicAdd(&se[m4.x], v.x);
                atomicAdd(&se[m4.y], v.y);
                atomicAdd(&se[m4.z], v.z);
                atomicAdd(&se[m4.w], v.w);
            }
        }
    }
    __syncthreads();
    float* gs = sums + (size_t)b * EDIM * NSEG;
    for (int i = threadIdx.x; i < EDIM * NSEG; i += TPB) {
        const float v = s_sum[i];
        if (v != 0.0f) atomicAdd(&gs[i], v);
    }
    if (threadIdx.x < NSEG) atomicAdd(&cnts[b * NSEG + threadIdx.x], s_cnt[threadIdx.x]);
}

// ---------------- block reduce helper ----------------
__device__ float block_reduce(float v, float* s_red) {
    s_red[threadIdx.x] = v;
    __syncthreads();
    for (int off = 128; off > 0; off >>= 1) {
        if ((int)threadIdx.x < off) s_red[threadIdx.x] += s_red[threadIdx.x + off];
        __syncthreads();
    }
    const float r = s_red[0];
    __syncthreads();
    return r;
}

// ---------------- pass 1.5: means + dist_loss + reg_loss per sample ----------------
__global__ __launch_bounds__(TPB) void k_means(const float* __restrict__ sums,
                                               const float* __restrict__ cnts,
                                               float* __restrict__ means_t,
                                               float* __restrict__ partials) {
    __shared__ float s_mu[EDIM * NSEG];
    __shared__ float s_cnt[NSEG];
    __shared__ float s_red[TPB];
    const int b = blockIdx.x;
    if (threadIdx.x < NSEG) s_cnt[threadIdx.x] = cnts[b * NSEG + threadIdx.x];
    __syncthreads();
    for (int i = threadIdx.x; i < EDIM * NSEG; i += TPB) {
        const int m = i % NSEG;
        const float mu = sums[(size_t)b * EDIM * NSEG + i] / fmaxf(s_cnt[m], 1.0f);
        s_mu[i] = mu;
        means_t[(size_t)b * EDIM * NSEG + i] = mu;
    }
    __syncthreads();

    // reg loss: instances m=1..32
    float reg = 0.0f, np = 0.0f;
    if (threadIdx.x >= 1 && threadIdx.x < NSEG) {
        float ss = 0.0f;
#pragma unroll
        for (int e = 0; e < EDIM; ++e) {
            const float v = s_mu[e * NSEG + threadIdx.x];
            ss += v * v;
        }
        reg = sqrtf(ss + 1e-12f);
        np = (s_cnt[threadIdx.x] > 0.0f) ? 1.0f : 0.0f;
    }

    // dist loss: 496 unordered pairs among instances 0..31 (mask values i+1)
    float dl = 0.0f;
    for (int p = threadIdx.x; p < (NINST * (NINST - 1)) / 2; p += TPB) {
        int i = 0, pp = p;
        while (pp >= NINST - 1 - i) { pp -= NINST - 1 - i; ++i; }
        const int j = i + 1 + pp;
        float sq = 0.0f;
#pragma unroll
        for (int e = 0; e < EDIM; ++e) {
            const float d = s_mu[e * NSEG + (i + 1)] - s_mu[e * NSEG + (j + 1)];
            sq += d * d;
        }
        const float pd = sqrtf(fmaxf(sq, 1e-12f));
        const float h = fmaxf(TWO_DELTA_D - pd, 0.0f);
        dl += h * h;
    }

    const float dl_t  = block_reduce(dl, s_red);
    const float reg_t = block_reduce(reg, s_red);
    const float np_t  = block_reduce(np, s_red);
    if (threadIdx.x == 0) {
        partials[b * 3 + 0] = dl_t / ((NINST * (NINST - 1)) / 2.0f);
        partials[b * 3 + 1] = reg_t / (float)NINST;
        partials[b * 3 + 2] = fmaxf(np_t, 1.0f);
    }
}

// ---------------- pass 2: hinged variance term ----------------
__global__ __launch_bounds__(TPB) void k_var(const float* __restrict__ emb,
                                             const int* __restrict__ msk,
                                             const float* __restrict__ means_t,
                                             float* __restrict__ varsums) {
    __shared__ float s_mu[EDIM * NSEG];
    __shared__ float s_var[NSEG];
    const int b = blockIdx.y;
    for (int i = threadIdx.x; i < EDIM * NSEG; i += TPB)
        s_mu[i] = means_t[(size_t)b * EDIM * NSEG + i];
    if (threadIdx.x < NSEG) s_var[threadIdx.x] = 0.0f;
    __syncthreads();

    const float* embB = emb + (size_t)b * EDIM * HW;
    const int*   mskB = msk + (size_t)b * HW;

    for (int t = blockIdx.x; t < NTILES; t += BPS) {
        const int p0 = t * TILE + threadIdx.x * PXT;
        const int4 m4 = *reinterpret_cast<const int4*>(mskB + p0);
        float d0 = 0.0f, d1 = 0.0f, d2 = 0.0f, d3 = 0.0f;

        float4 buf[2][EC];
#pragma unroll
        for (int e = 0; e < EC; ++e)
            buf[0][e] = *reinterpret_cast<const float4*>(embB + (size_t)e * HW + p0);
#pragma unroll
        for (int c = 0; c < NCHUNK; ++c) {
            if (c < NCHUNK - 1) {
#pragma unroll
                for (int e = 0; e < EC; ++e)
                    buf[(c + 1) & 1][e] = *reinterpret_cast<const float4*>(
                        embB + (size_t)((c + 1) * EC + e) * HW + p0);
            }
#pragma unroll
            for (int e = 0; e < EC; ++e) {
                const float4 v = buf[c & 1][e];
                const float* me = s_mu + (c * EC + e) * NSEG;
                const float t0 = v.x - me[m4.x]; d0 += t0 * t0;
                const float t1 = v.y - me[m4.y]; d1 += t1 * t1;
                const float t2 = v.z - me[m4.z]; d2 += t2 * t2;
                const float t3 = v.w - me[m4.w]; d3 += t3 * t3;
            }
        }
        if (m4.x > 0) { const float h = fmaxf(sqrtf(d0 + 1e-12f) - DELTA_V, 0.0f); atomicAdd(&s_var[m4.x], h * h); }
        if (m4.y > 0) { const float h = fmaxf(sqrtf(d1 + 1e-12f) - DELTA_V, 0.0f); atomicAdd(&s_var[m4.y], h * h); }
        if (m4.z > 0) { const float h = fmaxf(sqrtf(d2 + 1e-12f) - DELTA_V, 0.0f); atomicAdd(&s_var[m4.z], h * h); }
        if (m4.w > 0) { const float h = fmaxf(sqrtf(d3 + 1e-12f) - DELTA_V, 0.0f); atomicAdd(&s_var[m4.w], h * h); }
    }
    __syncthreads();
    if (threadIdx.x >= 1 && threadIdx.x < NSEG)
        atomicAdd(&varsums[b * NSEG + threadIdx.x], s_var[threadIdx.x]);
}

// ---------------- final: combine losses ----------------
__global__ void k_final(const float* __restrict__ varsums,
                        const float* __restrict__ cnts,
                        const float* __restrict__ partials,
                        float* __restrict__ out) {
    const int l = threadIdx.x;  // 64 threads, one wave
    float var_acc = 0.0f, dist_acc = 0.0f, reg_acc = 0.0f;
    for (int b = 0; b < BATCH; ++b) {
        float v = 0.0f;
        if (l >= 1 && l < NSEG) {
            const float c = cnts[b * NSEG + l];
            if (c > 0.0f) v = varsums[b * NSEG + l] / fmaxf(c, 1.0f);
        }
#pragma unroll
        for (int off = 32; off > 0; off >>= 1) v += __shfl_xor(v, off);
        var_acc  += v / partials[b * 3 + 2];
        dist_acc += partials[b * 3 + 0];
        reg_acc  += partials[b * 3 + 1];
    }
    if (l == 0) {
        const float var  = var_acc  / (float)BATCH;
        const float dist = dist_acc / (float)BATCH;
        const float reg  = reg_acc  / (float)BATCH;
        out[0] = ALPHA * var + BETA * dist + GAMMA * reg;
        out[1] = var;
        out[2] = dist;
        out[3] = reg;
    }
}

extern "C" void kernel_launch(void* const* d_in, const int* in_sizes, int n_in,
                              void* d_out, int out_size, void* d_ws, size_t ws_size,
                              hipStream_t stream) {
    const float* emb = (const float*)d_in[0];
    const int*   msk = (const int*)d_in[1];
    float* out = (float*)d_out;

    float* ws       = (float*)d_ws;
    float* sums     = ws;                                  // B*E*NSEG = 8448
    float* cnts     = sums + BATCH * EDIM * NSEG;          // B*NSEG   = 264
    float* varsums  = cnts + BATCH * NSEG;                 // B*NSEG   = 264
    float* means_t  = varsums + BATCH * NSEG;              // B*E*NSEG = 8448
    float* partials = means_t + BATCH * EDIM * NSEG;       // B*3      = 24

    const int nzero = BATCH * EDIM * NSEG + 2 * BATCH * NSEG;   // accumulators only
    k_zero<<<(nzero + TPB - 1) / TPB, TPB, 0, stream>>>(ws, nzero);

    dim3 grid(BPS, BATCH);
    k_segsum<<<grid, TPB, 0, stream>>>(emb, msk, sums, cnts);
    k_means<<<BATCH, TPB, 0, stream>>>(sums, cnts, means_t, partials);
    k_var<<<grid, TPB, 0, stream>>>(emb, msk, means_t, varsums);
    k_final<<<1, 64, 0, stream>>>(varsums, cnts, partials, out);
}

// Round 3
// 465.594 us; speedup vs baseline: 1.4850x; 1.4850x over previous
//
#include <hip/hip_runtime.h>
#include <hip/hip_bf16.h>
#include <math.h>

constexpr int BATCH = 8;
constexpr int EDIM  = 32;
constexpr int HDIM  = 512;
constexpr int WDIM  = 512;
constexpr int HW    = HDIM * WDIM;          // 262144 pixels per sample
constexpr int NSEG  = 33;                   // NUM_INST + 1
constexpr int NINST = 32;
constexpr float DELTA_V = 0.5f;
constexpr float TWO_DELTA_D = 3.0f;
constexpr float ALPHA = 1.0f, BETA = 1.0f, GAMMA = 0.001f;

constexpr int TPB  = 256;
constexpr int PXT  = 4;
constexpr int TILE = TPB * PXT;             // 1024 px per block-tile
constexpr int NTILES = HW / TILE;           // 256
constexpr int BPS  = 128;                   // blocks per sample
constexpr int MUP  = 36;                    // padded mu row length (floats), 16B-aligned rows

typedef __attribute__((ext_vector_type(8)))  short short8;
typedef __attribute__((ext_vector_type(16))) float f32x16;

__device__ inline short bfc(float f) {
    __hip_bfloat16 h = __float2bfloat16(f);
    short s;
    __builtin_memcpy(&s, &h, 2);
    return s;
}

// ---------------- workspace zeroing ----------------
__global__ void k_zero(float* __restrict__ p, int n) {
    int i = blockIdx.x * blockDim.x + threadIdx.x;
    if (i < n) p[i] = 0.0f;
}

// ---------------- pass 1: segment sums via one-hot MFMA + counts ----------------
// sums layout: [b][e*32 + n]  (n = bin-1, bins 1..32; bin 0 never needed by the loss)
__global__ __launch_bounds__(TPB) void k_segsum_mfma(const float* __restrict__ emb,
                                                     const int* __restrict__ msk,
                                                     float* __restrict__ sums,
                                                     float* __restrict__ cnts) {
    __shared__ float s_acc[4][EDIM * 32];
    __shared__ float s_cnt[NSEG];
    const int b    = blockIdx.y;
    const int tid  = threadIdx.x;
    const int lane = tid & 63;
    const int wid  = tid >> 6;

    if (tid < NSEG) s_cnt[tid] = 0.0f;
    __syncthreads();

    const float* embB = emb + (size_t)b * EDIM * HW;
    const int*   mskB = msk + (size_t)b * HW;
    const int blockStart = blockIdx.x * 2048;     // 2048 px per block
    const int waveBase   = blockStart + wid * 512;

    // ---- count phase: 512 px per wave, 8 per lane (few scattered atomics) ----
    {
        const int p = waveBase + lane * 8;
        const int4 c0 = *reinterpret_cast<const int4*>(mskB + p);
        const int4 c1 = *reinterpret_cast<const int4*>(mskB + p + 4);
        if (c0.x > 0) atomicAdd(&s_cnt[c0.x], 1.0f);
        if (c0.y > 0) atomicAdd(&s_cnt[c0.y], 1.0f);
        if (c0.z > 0) atomicAdd(&s_cnt[c0.z], 1.0f);
        if (c0.w > 0) atomicAdd(&s_cnt[c0.w], 1.0f);
        if (c1.x > 0) atomicAdd(&s_cnt[c1.x], 1.0f);
        if (c1.y > 0) atomicAdd(&s_cnt[c1.y], 1.0f);
        if (c1.z > 0) atomicAdd(&s_cnt[c1.z], 1.0f);
        if (c1.w > 0) atomicAdd(&s_cnt[c1.w], 1.0f);
    }

    // ---- MFMA loop: D[e][n] += emb_bf16[e][k] * onehot[k][n], 16 px per step ----
    const int e   = lane & 31;       // A row (and B col as bin index n)
    const int g   = lane >> 5;       // k sub-group
    const int binv = (lane & 31) + 1;
    const float* rowp = embB + (size_t)e * HW;

    f32x16 acc;
#pragma unroll
    for (int r = 0; r < 16; ++r) acc[r] = 0.0f;

    const int base0 = waveBase + 4 * g;
    float4 a0 = *reinterpret_cast<const float4*>(rowp + base0);
    float4 a1 = *reinterpret_cast<const float4*>(rowp + base0 + 8);
    int4   q0 = *reinterpret_cast<const int4*>(mskB + base0);
    int4   q1 = *reinterpret_cast<const int4*>(mskB + base0 + 8);

#pragma unroll
    for (int s = 0; s < 32; ++s) {
        float4 na0, na1; int4 nq0, nq1;
        if (s < 31) {
            const int np = base0 + (s + 1) * 16;
            na0 = *reinterpret_cast<const float4*>(rowp + np);
            na1 = *reinterpret_cast<const float4*>(rowp + np + 8);
            nq0 = *reinterpret_cast<const int4*>(mskB + np);
            nq1 = *reinterpret_cast<const int4*>(mskB + np + 8);
        }
        short8 afr, bfr;
        afr[0] = bfc(a0.x); afr[1] = bfc(a0.y); afr[2] = bfc(a0.z); afr[3] = bfc(a0.w);
        afr[4] = bfc(a1.x); afr[5] = bfc(a1.y); afr[6] = bfc(a1.z); afr[7] = bfc(a1.w);
        const short ONE = (short)0x3F80;
        bfr[0] = (q0.x == binv) ? ONE : (short)0;
        bfr[1] = (q0.y == binv) ? ONE : (short)0;
        bfr[2] = (q0.z == binv) ? ONE : (short)0;
        bfr[3] = (q0.w == binv) ? ONE : (short)0;
        bfr[4] = (q1.x == binv) ? ONE : (short)0;
        bfr[5] = (q1.y == binv) ? ONE : (short)0;
        bfr[6] = (q1.z == binv) ? ONE : (short)0;
        bfr[7] = (q1.w == binv) ? ONE : (short)0;
        acc = __builtin_amdgcn_mfma_f32_32x32x16_bf16(afr, bfr, acc, 0, 0, 0);
        a0 = na0; a1 = na1; q0 = nq0; q1 = nq1;
    }

    // ---- flush: C layout col=lane&31, row=(r&3)+8*(r>>2)+4*(lane>>5) ----
#pragma unroll
    for (int r = 0; r < 16; ++r) {
        const int row = (r & 3) + 8 * (r >> 2) + 4 * g;   // row = e index
        s_acc[wid][row * 32 + (lane & 31)] = acc[r];
    }
    __syncthreads();
    float* gs = sums + (size_t)b * EDIM * 32;
#pragma unroll
    for (int k = 0; k < 4; ++k) {
        const int i = tid * 4 + k;
        const float v = s_acc[0][i] + s_acc[1][i] + s_acc[2][i] + s_acc[3][i];
        atomicAdd(&gs[i], v);
    }
    if (tid >= 1 && tid < NSEG) atomicAdd(&cnts[b * NSEG + tid], s_cnt[tid]);
}

// ---------------- block reduce helper ----------------
__device__ float block_reduce(float v, float* s_red) {
    s_red[threadIdx.x] = v;
    __syncthreads();
    for (int off = 128; off > 0; off >>= 1) {
        if ((int)threadIdx.x < off) s_red[threadIdx.x] += s_red[threadIdx.x + off];
        __syncthreads();
    }
    const float r = s_red[0];
    __syncthreads();
    return r;
}

// ---------------- pass 1.5: means + dist/reg losses ----------------
// means_pad: [b][n][MUP] fp32 (n = bin-1), pad cols zeroed
__global__ __launch_bounds__(TPB) void k_means(const float* __restrict__ sums,
                                               const float* __restrict__ cnts,
                                               float* __restrict__ means_pad,
                                               float* __restrict__ partials) {
    __shared__ float s_mu[32][33];
    __shared__ float s_c[32];
    __shared__ float s_red[TPB];
    const int b = blockIdx.x;
    const int tid = threadIdx.x;
    if (tid < 32) s_c[tid] = cnts[b * NSEG + 1 + tid];
    __syncthreads();
    for (int i = tid; i < 32 * MUP; i += TPB) {
        const int n = i / MUP, e = i % MUP;
        float mu = 0.0f;
        if (e < 32) {
            mu = sums[(size_t)b * EDIM * 32 + e * 32 + n] / fmaxf(s_c[n], 1.0f);
            s_mu[n][e] = mu;
        }
        means_pad[(size_t)b * 32 * MUP + i] = mu;
    }
    __syncthreads();

    float reg = 0.0f, np = 0.0f;
    if (tid < 32) {
        float ss = 0.0f;
#pragma unroll
        for (int e = 0; e < EDIM; ++e) { const float v = s_mu[tid][e]; ss += v * v; }
        reg = sqrtf(ss + 1e-12f);
        np = (s_c[tid] > 0.0f) ? 1.0f : 0.0f;
    }

    float dl = 0.0f;
    for (int p = tid; p < (NINST * (NINST - 1)) / 2; p += TPB) {
        int i = 0, pp = p;
        while (pp >= NINST - 1 - i) { pp -= NINST - 1 - i; ++i; }
        const int j = i + 1 + pp;
        float sq = 0.0f;
#pragma unroll
        for (int e = 0; e < EDIM; ++e) {
            const float d = s_mu[i][e] - s_mu[j][e];
            sq += d * d;
        }
        const float pd = sqrtf(fmaxf(sq, 1e-12f));
        const float h = fmaxf(TWO_DELTA_D - pd, 0.0f);
        dl += h * h;
    }

    const float dl_t  = block_reduce(dl, s_red);
    const float reg_t = block_reduce(reg, s_red);
    const float np_t  = block_reduce(np, s_red);
    if (tid == 0) {
        partials[b * 3 + 0] = dl_t / ((NINST * (NINST - 1)) / 2.0f);
        partials[b * 3 + 1] = reg_t / (float)NINST;
        partials[b * 3 + 2] = fmaxf(np_t, 1.0f);
    }
}

// ---------------- pass 2: hinged variance (mu rows via b128, exact fp32) ----------------
__global__ __launch_bounds__(TPB) void k_var(const float* __restrict__ emb,
                                             const int* __restrict__ msk,
                                             const float* __restrict__ means_pad,
                                             float* __restrict__ varsums) {
    __shared__ __align__(16) float s_mu36[32 * MUP];
    __shared__ float s_var[NSEG];
    const int b = blockIdx.y;
    const int tid = threadIdx.x;
    for (int i = tid; i < 32 * MUP; i += TPB)
        s_mu36[i] = means_pad[(size_t)b * 32 * MUP + i];
    if (tid < NSEG) s_var[tid] = 0.0f;
    __syncthreads();

    const float* embB = emb + (size_t)b * EDIM * HW;
    const int*   mskB = msk + (size_t)b * HW;

    for (int t = blockIdx.x; t < NTILES; t += BPS) {
        const int p0 = t * TILE + tid * PXT;
        const int4 m4 = *reinterpret_cast<const int4*>(mskB + p0);
        const int r0 = (m4.x > 0 ? m4.x - 1 : 0) * MUP;
        const int r1 = (m4.y > 0 ? m4.y - 1 : 0) * MUP;
        const int r2 = (m4.z > 0 ? m4.z - 1 : 0) * MUP;
        const int r3 = (m4.w > 0 ? m4.w - 1 : 0) * MUP;
        float d0 = 0.0f, d1 = 0.0f, d2 = 0.0f, d3 = 0.0f;

        float4 buf[2][4];
#pragma unroll
        for (int j = 0; j < 4; ++j)
            buf[0][j] = *reinterpret_cast<const float4*>(embB + (size_t)j * HW + p0);
#pragma unroll
        for (int c = 0; c < 8; ++c) {
            if (c < 7) {
#pragma unroll
                for (int j = 0; j < 4; ++j)
                    buf[(c + 1) & 1][j] = *reinterpret_cast<const float4*>(
                        embB + (size_t)((c + 1) * 4 + j) * HW + p0);
            }
            const float4 M0 = *reinterpret_cast<const float4*>(&s_mu36[r0 + 4 * c]);
            const float4 M1 = *reinterpret_cast<const float4*>(&s_mu36[r1 + 4 * c]);
            const float4 M2 = *reinterpret_cast<const float4*>(&s_mu36[r2 + 4 * c]);
            const float4 M3 = *reinterpret_cast<const float4*>(&s_mu36[r3 + 4 * c]);
            const float4 E0 = buf[c & 1][0], E1 = buf[c & 1][1];
            const float4 E2 = buf[c & 1][2], E3 = buf[c & 1][3];
            float t0;
            t0 = E0.x - M0.x; d0 += t0 * t0;  t0 = E1.x - M0.y; d0 += t0 * t0;
            t0 = E2.x - M0.z; d0 += t0 * t0;  t0 = E3.x - M0.w; d0 += t0 * t0;
            t0 = E0.y - M1.x; d1 += t0 * t0;  t0 = E1.y - M1.y; d1 += t0 * t0;
            t0 = E2.y - M1.z; d1 += t0 * t0;  t0 = E3.y - M1.w; d1 += t0 * t0;
            t0 = E0.z - M2.x; d2 += t0 * t0;  t0 = E1.z - M2.y; d2 += t0 * t0;
            t0 = E2.z - M2.z; d2 += t0 * t0;  t0 = E3.z - M2.w; d2 += t0 * t0;
            t0 = E0.w - M3.x; d3 += t0 * t0;  t0 = E1.w - M3.y; d3 += t0 * t0;
            t0 = E2.w - M3.z; d3 += t0 * t0;  t0 = E3.w - M3.w; d3 += t0 * t0;
        }
        if (m4.x > 0) { const float h = fmaxf(sqrtf(d0 + 1e-12f) - DELTA_V, 0.0f); atomicAdd(&s_var[m4.x], h * h); }
        if (m4.y > 0) { const float h = fmaxf(sqrtf(d1 + 1e-12f) - DELTA_V, 0.0f); atomicAdd(&s_var[m4.y], h * h); }
        if (m4.z > 0) { const float h = fmaxf(sqrtf(d2 + 1e-12f) - DELTA_V, 0.0f); atomicAdd(&s_var[m4.z], h * h); }
        if (m4.w > 0) { const float h = fmaxf(sqrtf(d3 + 1e-12f) - DELTA_V, 0.0f); atomicAdd(&s_var[m4.w], h * h); }
    }
    __syncthreads();
    if (tid >= 1 && tid < NSEG)
        atomicAdd(&varsums[b * NSEG + tid], s_var[tid]);
}

// ---------------- final: combine ----------------
__global__ void k_final(const float* __restrict__ varsums,
                        const float* __restrict__ cnts,
                        const float* __restrict__ partials,
                        float* __restrict__ out) {
    const int l = threadIdx.x;
    float var_acc = 0.0f, dist_acc = 0.0f, reg_acc = 0.0f;
    for (int b = 0; b < BATCH; ++b) {
        float v = 0.0f;
        if (l >= 1 && l < NSEG) {
            const float c = cnts[b * NSEG + l];
            if (c > 0.0f) v = varsums[b * NSEG + l] / fmaxf(c, 1.0f);
        }
#pragma unroll
        for (int off = 32; off > 0; off >>= 1) v += __shfl_xor(v, off);
        var_acc  += v / partials[b * 3 + 2];
        dist_acc += partials[b * 3 + 0];
        reg_acc  += partials[b * 3 + 1];
    }
    if (l == 0) {
        const float var  = var_acc  / (float)BATCH;
        const float dist = dist_acc / (float)BATCH;
        const float reg  = reg_acc  / (float)BATCH;
        out[0] = ALPHA * var + BETA * dist + GAMMA * reg;
        out[1] = var;
        out[2] = dist;
        out[3] = reg;
    }
}

extern "C" void kernel_launch(void* const* d_in, const int* in_sizes, int n_in,
                              void* d_out, int out_size, void* d_ws, size_t ws_size,
                              hipStream_t stream) {
    const float* emb = (const float*)d_in[0];
    const int*   msk = (const int*)d_in[1];
    float* out = (float*)d_out;

    float* ws        = (float*)d_ws;
    float* sums      = ws;                                   // B*E*32   = 8192
    float* cnts      = sums + BATCH * EDIM * 32;             // B*NSEG   = 264
    float* varsums   = cnts + BATCH * NSEG;                  // B*NSEG   = 264
    float* means_pad = varsums + BATCH * NSEG;               // B*32*36  = 9216
    float* partials  = means_pad + BATCH * 32 * MUP;         // B*3      = 24

    const int nzero = BATCH * EDIM * 32 + 2 * BATCH * NSEG;  // sums + cnts + varsums
    k_zero<<<(nzero + TPB - 1) / TPB, TPB, 0, stream>>>(ws, nzero);

    dim3 grid(BPS, BATCH);
    k_segsum_mfma<<<grid, TPB, 0, stream>>>(emb, msk, sums, cnts);
    k_means<<<BATCH, TPB, 0, stream>>>(sums, cnts, means_pad, partials);
    k_var<<<grid, TPB, 0, stream>>>(emb, msk, means_pad, varsums);
    k_final<<<1, 64, 0, stream>>>(varsums, cnts, partials, out);
}